// Round 10
// baseline (426.540 us; speedup 1.0000x reference)
//
#include <hip/hip_runtime.h>
#include <hip/hip_bf16.h>

// CentroidsFlowAD: out[row] = sqrt(max(||e||^2 + min_col(||c||^2 - 2 e.c), 0))
// rows = 32*3136 = 100352, cols = 2048 centroids, K = 1024.
//
// Fast path (needs ~112 MiB ws), fp8 e4m3 cross-term (row norms exact fp32):
//   1. rowsq_fp8pack on centroids -> c8 (packed fp8, seg-128 layout) + csq
//   2. rowsq_fp8pack on embeds    -> e8 + esq
//   3. gemm_min_mx: 128x128 tile, BK=128, 4 waves (64x64), single-buffer
//      LDS 33 KB -> 4 blocks/CU. MX-scaled mfma_scale 16x16x128 (unit e8m0
//      scales). R10 fix: R9 spilled ~40 regs to scratch (WRITE_SIZE 489 MB,
//      the regression's entire cause) because offA/offB arrays (16 VGPR) +
//      b8[4]+a8 operands blew the 128-reg budget. Since row&7 == lr&7
//      (m*16 and wr*64 are 0 mod 8), the swizzle is m-invariant -> 4 base
//      addresses + imm offsets m*2048 replace the arrays. Live set ~122.
//   4. final_min: 16-way min + sqrt
// fp8 K-packed row layout (128B per K-seg of 128): 16B slot s=ksp*4+g holds
// k = {32*(2ksp)+8g..+7 | 32*(2ksp+1)+8g..+7}. Lane (g,lr) reading slots
// g and 4+g gets k-blocks 0..3 in register order = one x128 MFMA operand.
// Slot swizzle s^(row&7) (full 8-spread, proven R5-R9; R9 passed -> the
// x128 fragment layout and the mfma_scale call are verified correct).
// Fallback: round-1 fused kernel (proven, bf16).

typedef __bf16 bf16x8 __attribute__((ext_vector_type(8)));
typedef __bf16 bf16x4 __attribute__((ext_vector_type(4)));
typedef float f32x4 __attribute__((ext_vector_type(4)));
typedef int i32x4 __attribute__((ext_vector_type(4)));
typedef int i32x8 __attribute__((ext_vector_type(8)));

#define N_ROWS 100352
#define M_CENT 2048
#define D_K 1024

// fp8 fast-path geometry
#define BM4 128
#define BN4 128
#define BK4 128
#define NT4 (D_K / BK4)                // 8 K-tiles
#define NCT4 (M_CENT / BN4)            // 16 col tiles
#define NBLK4 ((N_ROWS / BM4) * NCT4)  // 12544
#define BPX4 (NBLK4 / 8)               // 1568 per XCD

// fallback geometry (round-1, unchanged)
#define TM 128
#define TN 128
#define BK 64
#define NT_TILES (M_CENT / TN)  // 16
#define KT_STEPS (D_K / BK)     // 16

#define AS1 __attribute__((address_space(1)))
#define AS3 __attribute__((address_space(3)))

#define WAITVM(N) asm volatile("s_waitcnt vmcnt(" #N ")" ::: "memory")
#define LGKM0 asm volatile("s_waitcnt lgkmcnt(0)" ::: "memory")
#define FENCE asm volatile("" ::: "memory")

// ---- prep: fp32 [rows][1024] -> packed fp8 row + per-row squared norm ----
// Packed byte position within row: seg(=128-K-seg)*128 + (ksp*4+g)*16 + h*8 + j
// where k = 32*(2*ksp+h) + 8*g + j.   (R5 layout, proven R5-R9.)
__global__ __launch_bounds__(256) void rowsq_fp8pack(const float* __restrict__ src,
                                                     unsigned char* __restrict__ dst,
                                                     float* __restrict__ sq) {
  const int m = blockIdx.x;   // row
  const int t = threadIdx.x;  // 256 threads * 4 floats = 1024
  const float4 v = *reinterpret_cast<const float4*>(src + (size_t)m * D_K + t * 4);
  int pk = __builtin_amdgcn_cvt_pk_fp8_f32(v.x, v.y, 0, false);
  pk = __builtin_amdgcn_cvt_pk_fp8_f32(v.z, v.w, pk, true);
  const int k = t * 4;
  const int seg = k >> 7;
  const int ksi = (k >> 5) & 3;
  const int g = (k >> 3) & 3;
  const int j = k & 7;  // 0 or 4
  const int p = seg * 128 + (((ksi >> 1) * 4 + g) << 4) + (ksi & 1) * 8 + j;
  *reinterpret_cast<unsigned int*>(dst + (size_t)m * D_K + p) = (unsigned int)pk;
  float ss = v.x * v.x + v.y * v.y + v.z * v.z + v.w * v.w;
  ss += __shfl_xor(ss, 1);
  ss += __shfl_xor(ss, 2);
  ss += __shfl_xor(ss, 4);
  ss += __shfl_xor(ss, 8);
  ss += __shfl_xor(ss, 16);
  ss += __shfl_xor(ss, 32);
  __shared__ float ws4[4];
  const int w = t >> 6, l = t & 63;
  if (l == 0) ws4[w] = ss;
  __syncthreads();
  if (t == 0) sq[m] = ws4[0] + ws4[1] + ws4[2] + ws4[3];
}

// ---- fast path: MX-scaled fp8, 128x128 tile, BK=128, single buf, 4 blk/CU ----
// LDS: A[128 rows][128 B] 16K | B[128][128 B] 16K = 32 KB (+1 KB rowmin).
// K-tile kt:
//   WAITVM(0) -> B1 (read-safety, all waves' stage landed)
//   16 ds_read_b128 -> 16 x mfma_scale 16x16x128 (compiler-interleaved)
//   LGKM0 -> B2 (WAR-safety) -> stage(kt+1)
// No setprio (R7). 4 blocks/CU phase-mixed TLP hides the drain (R8).
__global__ __launch_bounds__(256, 4) void gemm_min_mx(const unsigned char* __restrict__ e8,
                                                      const unsigned char* __restrict__ c8,
                                                      const float* __restrict__ csq,
                                                      float* __restrict__ pmin) {
  __shared__ __align__(16) char lds[32768];
  __shared__ float rowmin2[2][BM4];

  const int t = threadIdx.x;
  const int w = t >> 6;
  const int l = t & 63;
  const int wr = w >> 1, wc = w & 1;  // 2x2 wave grid, 64x64 tiles
  const int g = l >> 4, lr = l & 15;

  // XCD swizzle: XCD k owns swz in [1568k,1568k+1568) = rp in [98k,98k+98)
  // x all 16 ct. c8 (2 MB) L2-resident; A panel (128 KB) reused 16x L2-hot.
  const int b = blockIdx.x;
  const int swz = (b & 7) * BPX4 + (b >> 3);
  const int rp = swz >> 4, ct = swz & 15;
  const long row0 = (long)rp * BM4;
  const int col0 = ct * BN4;

  // staging: dest linear d = i*4096 + t*16 -> row = i*32 + (t>>3), slot = t&7
  // (row&7 i-invariant). source = row*1024 + kt*128 + ((slot^(row&7))<<4).
  const int trow = t >> 3, tsl = t & 7;
  const int ssw = (tsl ^ (trow & 7)) << 4;
  const unsigned char* srcA0 = e8 + (row0 + trow) * (size_t)D_K + ssw;
  const unsigned char* srcB0 = c8 + (size_t)(col0 + trow) * D_K + ssw;
  const int dst0 = t * 16;

  f32x4 acc[4][4];
#pragma unroll
  for (int m = 0; m < 4; ++m)
#pragma unroll
    for (int n = 0; n < 4; ++n) acc[m][n] = (f32x4){0.f, 0.f, 0.f, 0.f};

  // Lean frag addressing (R10): row&7 == lr&7 independent of m/wr, so the
  // swizzled slot offset is m-invariant. 4 base addrs + imm m*2048/n*2048.
  const int swsel = lr & 7;
  const char* aBase0 = lds + (wr * 64 + lr) * 128 + ((g ^ swsel) << 4);
  const char* aBase1 = lds + (wr * 64 + lr) * 128 + (((4 + g) ^ swsel) << 4);
  const char* bBase0 = lds + 16384 + (wc * 64 + lr) * 128 + ((g ^ swsel) << 4);
  const char* bBase1 = lds + 16384 + (wc * 64 + lr) * 128 + (((4 + g) ^ swsel) << 4);

  auto stage = [&](int kt) {
    const size_t ko = (size_t)kt * BK4;
#pragma unroll
    for (int i = 0; i < 4; ++i)
      __builtin_amdgcn_global_load_lds(
          (const AS1 unsigned int*)(const void*)(srcA0 + (size_t)i * 32 * D_K + ko),
          (AS3 unsigned int*)(void*)(lds + i * 4096 + dst0), 16, 0, 0);
#pragma unroll
    for (int i = 0; i < 4; ++i)
      __builtin_amdgcn_global_load_lds(
          (const AS1 unsigned int*)(const void*)(srcB0 + (size_t)i * 32 * D_K + ko),
          (AS3 unsigned int*)(void*)(lds + 16384 + i * 4096 + dst0), 16, 0, 0);
  };

  // read frags + MFMA for one K-tile (K=128 per MFMA, unit e8m0 scales)
  auto compute_tile = [&]() {
    i32x8 b8[4];
#pragma unroll
    for (int n = 0; n < 4; ++n) {
      const i32x4 lo = *reinterpret_cast<const i32x4*>(bBase0 + n * 2048);
      const i32x4 hi = *reinterpret_cast<const i32x4*>(bBase1 + n * 2048);
      b8[n] = __builtin_shufflevector(lo, hi, 0, 1, 2, 3, 4, 5, 6, 7);
    }
#pragma unroll
    for (int m = 0; m < 4; ++m) {
      const i32x4 lo = *reinterpret_cast<const i32x4*>(aBase0 + m * 2048);
      const i32x4 hi = *reinterpret_cast<const i32x4*>(aBase1 + m * 2048);
      const i32x8 a8 = __builtin_shufflevector(lo, hi, 0, 1, 2, 3, 4, 5, 6, 7);
#pragma unroll
      for (int n = 0; n < 4; ++n)
        acc[m][n] = __builtin_amdgcn_mfma_scale_f32_16x16x128_f8f6f4(
            a8, b8[n], acc[m][n], 0 /*fp8 A*/, 0 /*fp8 B*/, 0, 0x7F7F7F7F, 0,
            0x7F7F7F7F);
    }
  };

  stage(0);
#pragma unroll
  for (int kt = 0; kt < NT4; ++kt) {
    WAITVM(0);  // my stage(kt) landed (TLP across 4 blocks hides the drain)
    FENCE;
    __builtin_amdgcn_s_barrier();  // B1: tile kt fully landed (all waves)
    FENCE;
    compute_tile();
    if (kt < NT4 - 1) {
      LGKM0;  // all reads consumed by MFMAs already
      FENCE;
      __builtin_amdgcn_s_barrier();  // B2: all waves' reads done
      FENCE;
      stage(kt + 1);  // overwrite; lands before next WAITVM(0)
    }
  }

  // --- partial min over this block's 128 cols: val = ||c||^2 - 2*dot ---
  float runmin[4][4];
#pragma unroll
  for (int m = 0; m < 4; ++m)
#pragma unroll
    for (int r = 0; r < 4; ++r) runmin[m][r] = 3.0e38f;
#pragma unroll
  for (int n = 0; n < 4; ++n) {
    const float cs = csq[col0 + wc * 64 + n * 16 + lr];
#pragma unroll
    for (int m = 0; m < 4; ++m)
#pragma unroll
      for (int r = 0; r < 4; ++r)
        runmin[m][r] = fminf(runmin[m][r], cs - 2.0f * acc[m][n][r]);
  }
#pragma unroll
  for (int m = 0; m < 4; ++m)
#pragma unroll
    for (int r = 0; r < 4; ++r) {
      float v = runmin[m][r];
      v = fminf(v, __shfl_xor(v, 1));
      v = fminf(v, __shfl_xor(v, 2));
      v = fminf(v, __shfl_xor(v, 4));
      v = fminf(v, __shfl_xor(v, 8));
      runmin[m][r] = v;
    }
  if (lr == 0) {
#pragma unroll
    for (int m = 0; m < 4; ++m)
#pragma unroll
      for (int r = 0; r < 4; ++r)
        rowmin2[wc][wr * 64 + m * 16 + g * 4 + r] = runmin[m][r];
  }
  __syncthreads();
  if (t < BM4) {
    pmin[(row0 + t) * NCT4 + ct] = fminf(rowmin2[0][t], rowmin2[1][t]);
  }
}

// ---- final: 16-way min + sqrt ----
__global__ __launch_bounds__(256) void final_min(const float* __restrict__ esq,
                                                 const float* __restrict__ pmin,
                                                 float* __restrict__ out) {
  const int r = blockIdx.x * 256 + threadIdx.x;
  const float4* p = reinterpret_cast<const float4*>(pmin + (size_t)r * 16);
  float4 a = p[0], b = p[1], c = p[2], d = p[3];
  float m = fminf(fminf(fminf(a.x, a.y), fminf(a.z, a.w)),
                  fminf(fminf(b.x, b.y), fminf(b.z, b.w)));
  m = fminf(m, fminf(fminf(fminf(c.x, c.y), fminf(c.z, c.w)),
                     fminf(fminf(d.x, d.y), fminf(d.z, d.w))));
  out[r] = sqrtf(fmaxf(esq[r] + m, 0.f));
}

// ---- bf16 prep (fallback path) ----
__global__ __launch_bounds__(256) void rowsq_bf16(const float* __restrict__ src,
                                                  __bf16* __restrict__ dst,
                                                  float* __restrict__ sq) {
  const int m = blockIdx.x;
  const int t = threadIdx.x;
  const float4 v = *reinterpret_cast<const float4*>(src + (size_t)m * D_K + t * 4);
  bf16x4 o = {(__bf16)v.x, (__bf16)v.y, (__bf16)v.z, (__bf16)v.w};
  *reinterpret_cast<bf16x4*>(dst + (size_t)m * D_K + t * 4) = o;
  float ss = v.x * v.x + v.y * v.y + v.z * v.z + v.w * v.w;
  ss += __shfl_xor(ss, 1);
  ss += __shfl_xor(ss, 2);
  ss += __shfl_xor(ss, 4);
  ss += __shfl_xor(ss, 8);
  ss += __shfl_xor(ss, 16);
  ss += __shfl_xor(ss, 32);
  __shared__ float ws4[4];
  const int w = t >> 6, l = t & 63;
  if (l == 0) ws4[w] = ss;
  __syncthreads();
  if (t == 0) sq[m] = ws4[0] + ws4[1] + ws4[2] + ws4[3];
}

// =================== round-1 fallback (proven) ===================
template <bool WS>
__global__ __launch_bounds__(256, 2) void fused_min(const float* __restrict__ embeds,
                                                    const float* __restrict__ centf,
                                                    const __bf16* __restrict__ cbf,
                                                    const float* __restrict__ csq,
                                                    float* __restrict__ out) {
  __shared__ __align__(16) char Ab[TM * 128];
  __shared__ __align__(16) char Bb[TN * 128];
  __shared__ float rowmin2[2][TM];
  __shared__ float sqrow[TM];
  __shared__ float colsq[TN];

  const int t = threadIdx.x;
  const int w = t >> 6;
  const int l = t & 63;
  const int wr = w >> 1, wc = w & 1;
  const int g = l >> 4, lr = l & 15;
  const long row0 = (long)blockIdx.x * TM;

  float runmin[4][4];
#pragma unroll
  for (int m = 0; m < 4; ++m)
#pragma unroll
    for (int r = 0; r < 4; ++r) runmin[m][r] = 3.0e38f;

  float sqpart[8];
#pragma unroll
  for (int c = 0; c < 8; ++c) sqpart[c] = 0.f;

  for (int nt = 0; nt < NT_TILES; ++nt) {
    const int col0 = nt * TN;
    f32x4 acc[4][4];
#pragma unroll
    for (int m = 0; m < 4; ++m)
#pragma unroll
      for (int n = 0; n < 4; ++n) acc[m][n] = (f32x4){0.f, 0.f, 0.f, 0.f};

    float cpart[8];
    if constexpr (!WS) {
#pragma unroll
      for (int c = 0; c < 8; ++c) cpart[c] = 0.f;
    }

    for (int kt = 0; kt < KT_STEPS; ++kt) {
      __syncthreads();
      if constexpr (WS) {
#pragma unroll
        for (int i = 0; i < 4; ++i) {
          const int s = (w * 4 + i) * 64 + l;
          const int col = s >> 3, sl = s & 7;
          const __bf16* src =
              cbf + (size_t)(col0 + col) * D_K + kt * BK + ((sl ^ (col & 7)) << 3);
          __builtin_amdgcn_global_load_lds(
              (const AS1 unsigned int*)(const void*)src,
              (AS3 unsigned int*)(void*)(Bb + (w * 4 + i) * 1024), 16, 0, 0);
        }
      } else {
#pragma unroll
        for (int c = 0; c < 8; ++c) {
          const int f = c * 256 + t;
          const int col = f >> 4, kq = f & 15;
          const float4 v = *reinterpret_cast<const float4*>(
              centf + (size_t)(col0 + col) * D_K + kt * BK + kq * 4);
          cpart[c] += v.x * v.x + v.y * v.y + v.z * v.z + v.w * v.w;
          bf16x4 o = {(__bf16)v.x, (__bf16)v.y, (__bf16)v.z, (__bf16)v.w};
          const int slot = kq >> 1;
          *reinterpret_cast<bf16x4*>(Bb + col * 128 + ((slot ^ (col & 7)) << 4) +
                                     (kq & 1) * 8) = o;
        }
      }
#pragma unroll
      for (int c = 0; c < 8; ++c) {
        const int f = c * 256 + t;
        const int row = f >> 4, kq = f & 15;
        const float4 v = *reinterpret_cast<const float4*>(
            embeds + (row0 + row) * (long)D_K + kt * BK + kq * 4);
        if (nt == 0) sqpart[c] += v.x * v.x + v.y * v.y + v.z * v.z + v.w * v.w;
        bf16x4 o = {(__bf16)v.x, (__bf16)v.y, (__bf16)v.z, (__bf16)v.w};
        const int slot = kq >> 1;
        *reinterpret_cast<bf16x4*>(Ab + row * 128 + ((slot ^ (row & 7)) << 4) +
                                   (kq & 1) * 8) = o;
      }
      __syncthreads();
#pragma unroll
      for (int ks = 0; ks < 2; ++ks) {
        bf16x8 af[4], bfr[4];
#pragma unroll
        for (int m = 0; m < 4; ++m) {
          const int row = wr * 64 + m * 16 + lr;
          const int slot = ks * 4 + g;
          af[m] = *reinterpret_cast<const bf16x8*>(Ab + row * 128 +
                                                   ((slot ^ (row & 7)) << 4));
        }
#pragma unroll
        for (int n = 0; n < 4; ++n) {
          const int col = wc * 64 + n * 16 + lr;
          const int slot = ks * 4 + g;
          bfr[n] = *reinterpret_cast<const bf16x8*>(Bb + col * 128 +
                                                    ((slot ^ (col & 7)) << 4));
        }
#pragma unroll
        for (int m = 0; m < 4; ++m)
#pragma unroll
          for (int n = 0; n < 4; ++n)
            acc[m][n] =
                __builtin_amdgcn_mfma_f32_16x16x32_bf16(af[m], bfr[n], acc[m][n], 0, 0, 0);
      }
    }

    if (nt == 0) {
#pragma unroll
      for (int c = 0; c < 8; ++c) {
        float ss = sqpart[c];
        ss += __shfl_xor(ss, 1);
        ss += __shfl_xor(ss, 2);
        ss += __shfl_xor(ss, 4);
        ss += __shfl_xor(ss, 8);
        if (lr == 0) sqrow[c * 16 + (w * 4 + g)] = ss;
      }
    }
    if constexpr (!WS) {
#pragma unroll
      for (int c = 0; c < 8; ++c) {
        float ss = cpart[c];
        ss += __shfl_xor(ss, 1);
        ss += __shfl_xor(ss, 2);
        ss += __shfl_xor(ss, 4);
        ss += __shfl_xor(ss, 8);
        if (lr == 0) colsq[c * 16 + (w * 4 + g)] = ss;
      }
      __syncthreads();
    }

#pragma unroll
    for (int n = 0; n < 4; ++n) {
      float cs;
      if constexpr (WS)
        cs = csq[col0 + wc * 64 + n * 16 + lr];
      else
        cs = colsq[wc * 64 + n * 16 + lr];
#pragma unroll
      for (int m = 0; m < 4; ++m)
#pragma unroll
        for (int r = 0; r < 4; ++r)
          runmin[m][r] = fminf(runmin[m][r], cs - 2.0f * acc[m][n][r]);
    }
  }

#pragma unroll
  for (int m = 0; m < 4; ++m)
#pragma unroll
    for (int r = 0; r < 4; ++r) {
      float v = runmin[m][r];
      v = fminf(v, __shfl_xor(v, 1));
      v = fminf(v, __shfl_xor(v, 2));
      v = fminf(v, __shfl_xor(v, 4));
      v = fminf(v, __shfl_xor(v, 8));
      runmin[m][r] = v;
    }
  if (lr == 0) {
#pragma unroll
    for (int m = 0; m < 4; ++m)
#pragma unroll
      for (int r = 0; r < 4; ++r)
        rowmin2[wc][wr * 64 + m * 16 + g * 4 + r] = runmin[m][r];
  }
  __syncthreads();
  if (t < TM) {
    const float v = fminf(rowmin2[0][t], rowmin2[1][t]);
    out[row0 + t] = sqrtf(fmaxf(sqrow[t] + v, 0.f));
  }
}

extern "C" void kernel_launch(void* const* d_in, const int* in_sizes, int n_in,
                              void* d_out, int out_size, void* d_ws, size_t ws_size,
                              hipStream_t stream) {
  const float* embeds = (const float*)d_in[0];
  const float* cent = (const float*)d_in[1];
  float* out = (float*)d_out;

  // ws layout for the fp8 fast path (~112 MiB)
  const size_t off_c8 = 0;
  const size_t off_csq = off_c8 + (size_t)M_CENT * D_K;             // 2 MiB
  const size_t off_e8 = off_csq + (size_t)M_CENT * 4;               // +8 KiB
  const size_t off_esq = off_e8 + (size_t)N_ROWS * D_K;             // +98 MiB
  const size_t off_pmin = off_esq + (size_t)N_ROWS * 4;             // +392 KiB
  const size_t need_full = off_pmin + (size_t)N_ROWS * NCT4 * 4;    // +6.1 MiB
  const size_t need_small = (size_t)M_CENT * D_K * 2 + (size_t)M_CENT * 4;

  if (ws_size >= need_full) {
    unsigned char* c8 = (unsigned char*)d_ws + off_c8;
    float* csq = (float*)((char*)d_ws + off_csq);
    unsigned char* e8 = (unsigned char*)d_ws + off_e8;
    float* esq = (float*)((char*)d_ws + off_esq);
    float* pmin = (float*)((char*)d_ws + off_pmin);
    rowsq_fp8pack<<<M_CENT, 256, 0, stream>>>(cent, c8, csq);
    rowsq_fp8pack<<<N_ROWS, 256, 0, stream>>>(embeds, e8, esq);
    gemm_min_mx<<<NBLK4, 256, 0, stream>>>(e8, c8, csq, pmin);
    final_min<<<N_ROWS / 256, 256, 0, stream>>>(esq, pmin, out);
  } else if (ws_size >= need_small) {
    __bf16* cbf = (__bf16*)d_ws;
    float* csq = (float*)((char*)d_ws + (size_t)M_CENT * D_K * 2);
    rowsq_bf16<<<M_CENT, 256, 0, stream>>>(cent, cbf, csq);
    fused_min<true><<<N_ROWS / TM, 256, 0, stream>>>(embeds, cent, cbf, csq, out);
  } else {
    fused_min<false><<<N_ROWS / TM, 256, 0, stream>>>(embeds, cent, nullptr, nullptr, out);
  }
}

// Round 11
// 320.050 us; speedup vs baseline: 1.3327x; 1.3327x over previous
//
#include <hip/hip_runtime.h>
#include <hip/hip_bf16.h>

// CentroidsFlowAD: out[row] = sqrt(max(||e||^2 + min_col(||c||^2 - 2 e.c), 0))
// rows = 32*3136 = 100352, cols = 2048 centroids, K = 1024.
//
// Fast path (needs ~112 MiB ws), fp8 e4m3 cross-term (row norms exact fp32):
//   1. rowsq_fp8pack on centroids -> c8 (packed fp8, seg-128 layout) + csq
//   2. rowsq_fp8pack on embeds    -> e8 + esq
//   3. gemm_min_mx: 128x128 tile, BK=128, 4 waves (64x64), single-buffer
//      LDS 33 KB. MX-scaled mfma_scale 16x16x128 (unit e8m0 scales).
//      R11 fix: launch_bounds(256,4) gave a 128-reg UNIFIED budget
//      (gfx950 unified VGPR/AGPR); acc=64 left only 64 arch regs vs a
//      ~80-reg working set -> structural spill (R9/R10: WRITE_SIZE 516 MB,
//      VGPR pinned at 64). (256,3) -> 168-reg budget, no spill, 3 blk/CU.
//      With MX the binding pipe is the per-CU LDS (shared across blocks,
//      ~165 us serial floor) -- 3 blocks/CU keeps it fed; 4 was only
//      needed when MFMA was the long pole (R8).
//   4. final_min: 16-way min + sqrt
// fp8 K-packed row layout (128B per K-seg of 128): 16B slot s=ksp*4+g holds
// k = {32*(2ksp)+8g..+7 | 32*(2ksp+1)+8g..+7}. Lane (g,lr) reading slots
// g and 4+g gets k-blocks 0..3 in register order = one x128 MFMA operand.
// Slot swizzle s^(row&7) (full 8-spread; R9/R10 passed -> x128 fragment
// layout and the mfma_scale call are verified correct).
// Fallback: round-1 fused kernel (proven, bf16).

typedef __bf16 bf16x8 __attribute__((ext_vector_type(8)));
typedef __bf16 bf16x4 __attribute__((ext_vector_type(4)));
typedef float f32x4 __attribute__((ext_vector_type(4)));
typedef int i32x4 __attribute__((ext_vector_type(4)));
typedef int i32x8 __attribute__((ext_vector_type(8)));

#define N_ROWS 100352
#define M_CENT 2048
#define D_K 1024

// fp8 fast-path geometry
#define BM4 128
#define BN4 128
#define BK4 128
#define NT4 (D_K / BK4)                // 8 K-tiles
#define NCT4 (M_CENT / BN4)            // 16 col tiles
#define NBLK4 ((N_ROWS / BM4) * NCT4)  // 12544
#define BPX4 (NBLK4 / 8)               // 1568 per XCD

// fallback geometry (round-1, unchanged)
#define TM 128
#define TN 128
#define BK 64
#define NT_TILES (M_CENT / TN)  // 16
#define KT_STEPS (D_K / BK)     // 16

#define AS1 __attribute__((address_space(1)))
#define AS3 __attribute__((address_space(3)))

#define WAITVM(N) asm volatile("s_waitcnt vmcnt(" #N ")" ::: "memory")
#define LGKM0 asm volatile("s_waitcnt lgkmcnt(0)" ::: "memory")
#define FENCE asm volatile("" ::: "memory")

// ---- prep: fp32 [rows][1024] -> packed fp8 row + per-row squared norm ----
// Packed byte position within row: seg(=128-K-seg)*128 + (ksp*4+g)*16 + h*8 + j
// where k = 32*(2*ksp+h) + 8*g + j.   (R5 layout, proven R5-R10.)
__global__ __launch_bounds__(256) void rowsq_fp8pack(const float* __restrict__ src,
                                                     unsigned char* __restrict__ dst,
                                                     float* __restrict__ sq) {
  const int m = blockIdx.x;   // row
  const int t = threadIdx.x;  // 256 threads * 4 floats = 1024
  const float4 v = *reinterpret_cast<const float4*>(src + (size_t)m * D_K + t * 4);
  int pk = __builtin_amdgcn_cvt_pk_fp8_f32(v.x, v.y, 0, false);
  pk = __builtin_amdgcn_cvt_pk_fp8_f32(v.z, v.w, pk, true);
  const int k = t * 4;
  const int seg = k >> 7;
  const int ksi = (k >> 5) & 3;
  const int g = (k >> 3) & 3;
  const int j = k & 7;  // 0 or 4
  const int p = seg * 128 + (((ksi >> 1) * 4 + g) << 4) + (ksi & 1) * 8 + j;
  *reinterpret_cast<unsigned int*>(dst + (size_t)m * D_K + p) = (unsigned int)pk;
  float ss = v.x * v.x + v.y * v.y + v.z * v.z + v.w * v.w;
  ss += __shfl_xor(ss, 1);
  ss += __shfl_xor(ss, 2);
  ss += __shfl_xor(ss, 4);
  ss += __shfl_xor(ss, 8);
  ss += __shfl_xor(ss, 16);
  ss += __shfl_xor(ss, 32);
  __shared__ float ws4[4];
  const int w = t >> 6, l = t & 63;
  if (l == 0) ws4[w] = ss;
  __syncthreads();
  if (t == 0) sq[m] = ws4[0] + ws4[1] + ws4[2] + ws4[3];
}

// ---- fast path: MX-scaled fp8, 128x128 tile, BK=128, single buf, 3 blk/CU ----
// LDS: A[128 rows][128 B] 16K | B[128][128 B] 16K = 32 KB (+1 KB rowmin).
// K-tile kt:
//   WAITVM(0) -> B1 (read-safety, all waves' stage landed)
//   16 ds_read_b128 -> 16 x mfma_scale 16x16x128 (compiler-interleaved)
//   LGKM0 -> B2 (WAR-safety) -> stage(kt+1)
// No setprio (R7).
__global__ __launch_bounds__(256, 3) void gemm_min_mx(const unsigned char* __restrict__ e8,
                                                      const unsigned char* __restrict__ c8,
                                                      const float* __restrict__ csq,
                                                      float* __restrict__ pmin) {
  __shared__ __align__(16) char lds[32768];
  __shared__ float rowmin2[2][BM4];

  const int t = threadIdx.x;
  const int w = t >> 6;
  const int l = t & 63;
  const int wr = w >> 1, wc = w & 1;  // 2x2 wave grid, 64x64 tiles
  const int g = l >> 4, lr = l & 15;

  // XCD swizzle: XCD k owns swz in [1568k,1568k+1568) = rp in [98k,98k+98)
  // x all 16 ct. c8 (2 MB) L2-resident; A panel (128 KB) reused 16x L2-hot.
  const int b = blockIdx.x;
  const int swz = (b & 7) * BPX4 + (b >> 3);
  const int rp = swz >> 4, ct = swz & 15;
  const long row0 = (long)rp * BM4;
  const int col0 = ct * BN4;

  // staging: dest linear d = i*4096 + t*16 -> row = i*32 + (t>>3), slot = t&7
  // (row&7 i-invariant). source = row*1024 + kt*128 + ((slot^(row&7))<<4).
  const int trow = t >> 3, tsl = t & 7;
  const int ssw = (tsl ^ (trow & 7)) << 4;
  const unsigned char* srcA0 = e8 + (row0 + trow) * (size_t)D_K + ssw;
  const unsigned char* srcB0 = c8 + (size_t)(col0 + trow) * D_K + ssw;
  const int dst0 = t * 16;

  f32x4 acc[4][4];
#pragma unroll
  for (int m = 0; m < 4; ++m)
#pragma unroll
    for (int n = 0; n < 4; ++n) acc[m][n] = (f32x4){0.f, 0.f, 0.f, 0.f};

  // Lean frag addressing: row&7 == lr&7 independent of m/wr, so the
  // swizzled slot offset is m-invariant. 4 base addrs + imm m*2048/n*2048.
  const int swsel = lr & 7;
  const char* aBase0 = lds + (wr * 64 + lr) * 128 + ((g ^ swsel) << 4);
  const char* aBase1 = lds + (wr * 64 + lr) * 128 + (((4 + g) ^ swsel) << 4);
  const char* bBase0 = lds + 16384 + (wc * 64 + lr) * 128 + ((g ^ swsel) << 4);
  const char* bBase1 = lds + 16384 + (wc * 64 + lr) * 128 + (((4 + g) ^ swsel) << 4);

  auto stage = [&](int kt) {
    const size_t ko = (size_t)kt * BK4;
#pragma unroll
    for (int i = 0; i < 4; ++i)
      __builtin_amdgcn_global_load_lds(
          (const AS1 unsigned int*)(const void*)(srcA0 + (size_t)i * 32 * D_K + ko),
          (AS3 unsigned int*)(void*)(lds + i * 4096 + dst0), 16, 0, 0);
#pragma unroll
    for (int i = 0; i < 4; ++i)
      __builtin_amdgcn_global_load_lds(
          (const AS1 unsigned int*)(const void*)(srcB0 + (size_t)i * 32 * D_K + ko),
          (AS3 unsigned int*)(void*)(lds + 16384 + i * 4096 + dst0), 16, 0, 0);
  };

  // read frags + MFMA for one K-tile (K=128 per MFMA, unit e8m0 scales)
  auto compute_tile = [&]() {
    i32x8 b8[4];
#pragma unroll
    for (int n = 0; n < 4; ++n) {
      const i32x4 lo = *reinterpret_cast<const i32x4*>(bBase0 + n * 2048);
      const i32x4 hi = *reinterpret_cast<const i32x4*>(bBase1 + n * 2048);
      b8[n] = __builtin_shufflevector(lo, hi, 0, 1, 2, 3, 4, 5, 6, 7);
    }
#pragma unroll
    for (int m = 0; m < 4; ++m) {
      const i32x4 lo = *reinterpret_cast<const i32x4*>(aBase0 + m * 2048);
      const i32x4 hi = *reinterpret_cast<const i32x4*>(aBase1 + m * 2048);
      const i32x8 a8 = __builtin_shufflevector(lo, hi, 0, 1, 2, 3, 4, 5, 6, 7);
#pragma unroll
      for (int n = 0; n < 4; ++n)
        acc[m][n] = __builtin_amdgcn_mfma_scale_f32_16x16x128_f8f6f4(
            a8, b8[n], acc[m][n], 0 /*fp8 A*/, 0 /*fp8 B*/, 0, 0x7F7F7F7F, 0,
            0x7F7F7F7F);
    }
  };

  stage(0);
#pragma unroll
  for (int kt = 0; kt < NT4; ++kt) {
    WAITVM(0);  // my stage(kt) landed (cross-block TLP hides the drain)
    FENCE;
    __builtin_amdgcn_s_barrier();  // B1: tile kt fully landed (all waves)
    FENCE;
    compute_tile();
    if (kt < NT4 - 1) {
      LGKM0;  // all reads consumed by MFMAs already
      FENCE;
      __builtin_amdgcn_s_barrier();  // B2: all waves' reads done
      FENCE;
      stage(kt + 1);  // overwrite; lands before next WAITVM(0)
    }
  }

  // --- partial min over this block's 128 cols: val = ||c||^2 - 2*dot ---
  float runmin[4][4];
#pragma unroll
  for (int m = 0; m < 4; ++m)
#pragma unroll
    for (int r = 0; r < 4; ++r) runmin[m][r] = 3.0e38f;
#pragma unroll
  for (int n = 0; n < 4; ++n) {
    const float cs = csq[col0 + wc * 64 + n * 16 + lr];
#pragma unroll
    for (int m = 0; m < 4; ++m)
#pragma unroll
      for (int r = 0; r < 4; ++r)
        runmin[m][r] = fminf(runmin[m][r], cs - 2.0f * acc[m][n][r]);
  }
#pragma unroll
  for (int m = 0; m < 4; ++m)
#pragma unroll
    for (int r = 0; r < 4; ++r) {
      float v = runmin[m][r];
      v = fminf(v, __shfl_xor(v, 1));
      v = fminf(v, __shfl_xor(v, 2));
      v = fminf(v, __shfl_xor(v, 4));
      v = fminf(v, __shfl_xor(v, 8));
      runmin[m][r] = v;
    }
  if (lr == 0) {
#pragma unroll
    for (int m = 0; m < 4; ++m)
#pragma unroll
      for (int r = 0; r < 4; ++r)
        rowmin2[wc][wr * 64 + m * 16 + g * 4 + r] = runmin[m][r];
  }
  __syncthreads();
  if (t < BM4) {
    pmin[(row0 + t) * NCT4 + ct] = fminf(rowmin2[0][t], rowmin2[1][t]);
  }
}

// ---- final: 16-way min + sqrt ----
__global__ __launch_bounds__(256) void final_min(const float* __restrict__ esq,
                                                 const float* __restrict__ pmin,
                                                 float* __restrict__ out) {
  const int r = blockIdx.x * 256 + threadIdx.x;
  const float4* p = reinterpret_cast<const float4*>(pmin + (size_t)r * 16);
  float4 a = p[0], b = p[1], c = p[2], d = p[3];
  float m = fminf(fminf(fminf(a.x, a.y), fminf(a.z, a.w)),
                  fminf(fminf(b.x, b.y), fminf(b.z, b.w)));
  m = fminf(m, fminf(fminf(fminf(c.x, c.y), fminf(c.z, c.w)),
                     fminf(fminf(d.x, d.y), fminf(d.z, d.w))));
  out[r] = sqrtf(fmaxf(esq[r] + m, 0.f));
}

// ---- bf16 prep (fallback path) ----
__global__ __launch_bounds__(256) void rowsq_bf16(const float* __restrict__ src,
                                                  __bf16* __restrict__ dst,
                                                  float* __restrict__ sq) {
  const int m = blockIdx.x;
  const int t = threadIdx.x;
  const float4 v = *reinterpret_cast<const float4*>(src + (size_t)m * D_K + t * 4);
  bf16x4 o = {(__bf16)v.x, (__bf16)v.y, (__bf16)v.z, (__bf16)v.w};
  *reinterpret_cast<bf16x4*>(dst + (size_t)m * D_K + t * 4) = o;
  float ss = v.x * v.x + v.y * v.y + v.z * v.z + v.w * v.w;
  ss += __shfl_xor(ss, 1);
  ss += __shfl_xor(ss, 2);
  ss += __shfl_xor(ss, 4);
  ss += __shfl_xor(ss, 8);
  ss += __shfl_xor(ss, 16);
  ss += __shfl_xor(ss, 32);
  __shared__ float ws4[4];
  const int w = t >> 6, l = t & 63;
  if (l == 0) ws4[w] = ss;
  __syncthreads();
  if (t == 0) sq[m] = ws4[0] + ws4[1] + ws4[2] + ws4[3];
}

// =================== round-1 fallback (proven) ===================
template <bool WS>
__global__ __launch_bounds__(256, 2) void fused_min(const float* __restrict__ embeds,
                                                    const float* __restrict__ centf,
                                                    const __bf16* __restrict__ cbf,
                                                    const float* __restrict__ csq,
                                                    float* __restrict__ out) {
  __shared__ __align__(16) char Ab[TM * 128];
  __shared__ __align__(16) char Bb[TN * 128];
  __shared__ float rowmin2[2][TM];
  __shared__ float sqrow[TM];
  __shared__ float colsq[TN];

  const int t = threadIdx.x;
  const int w = t >> 6;
  const int l = t & 63;
  const int wr = w >> 1, wc = w & 1;
  const int g = l >> 4, lr = l & 15;
  const long row0 = (long)blockIdx.x * TM;

  float runmin[4][4];
#pragma unroll
  for (int m = 0; m < 4; ++m)
#pragma unroll
    for (int r = 0; r < 4; ++r) runmin[m][r] = 3.0e38f;

  float sqpart[8];
#pragma unroll
  for (int c = 0; c < 8; ++c) sqpart[c] = 0.f;

  for (int nt = 0; nt < NT_TILES; ++nt) {
    const int col0 = nt * TN;
    f32x4 acc[4][4];
#pragma unroll
    for (int m = 0; m < 4; ++m)
#pragma unroll
      for (int n = 0; n < 4; ++n) acc[m][n] = (f32x4){0.f, 0.f, 0.f, 0.f};

    float cpart[8];
    if constexpr (!WS) {
#pragma unroll
      for (int c = 0; c < 8; ++c) cpart[c] = 0.f;
    }

    for (int kt = 0; kt < KT_STEPS; ++kt) {
      __syncthreads();
      if constexpr (WS) {
#pragma unroll
        for (int i = 0; i < 4; ++i) {
          const int s = (w * 4 + i) * 64 + l;
          const int col = s >> 3, sl = s & 7;
          const __bf16* src =
              cbf + (size_t)(col0 + col) * D_K + kt * BK + ((sl ^ (col & 7)) << 3);
          __builtin_amdgcn_global_load_lds(
              (const AS1 unsigned int*)(const void*)src,
              (AS3 unsigned int*)(void*)(Bb + (w * 4 + i) * 1024), 16, 0, 0);
        }
      } else {
#pragma unroll
        for (int c = 0; c < 8; ++c) {
          const int f = c * 256 + t;
          const int col = f >> 4, kq = f & 15;
          const float4 v = *reinterpret_cast<const float4*>(
              centf + (size_t)(col0 + col) * D_K + kt * BK + kq * 4);
          cpart[c] += v.x * v.x + v.y * v.y + v.z * v.z + v.w * v.w;
          bf16x4 o = {(__bf16)v.x, (__bf16)v.y, (__bf16)v.z, (__bf16)v.w};
          const int slot = kq >> 1;
          *reinterpret_cast<bf16x4*>(Bb + col * 128 + ((slot ^ (col & 7)) << 4) +
                                     (kq & 1) * 8) = o;
        }
      }
#pragma unroll
      for (int c = 0; c < 8; ++c) {
        const int f = c * 256 + t;
        const int row = f >> 4, kq = f & 15;
        const float4 v = *reinterpret_cast<const float4*>(
            embeds + (row0 + row) * (long)D_K + kt * BK + kq * 4);
        if (nt == 0) sqpart[c] += v.x * v.x + v.y * v.y + v.z * v.z + v.w * v.w;
        bf16x4 o = {(__bf16)v.x, (__bf16)v.y, (__bf16)v.z, (__bf16)v.w};
        const int slot = kq >> 1;
        *reinterpret_cast<bf16x4*>(Ab + row * 128 + ((slot ^ (row & 7)) << 4) +
                                   (kq & 1) * 8) = o;
      }
      __syncthreads();
#pragma unroll
      for (int ks = 0; ks < 2; ++ks) {
        bf16x8 af[4], bfr[4];
#pragma unroll
        for (int m = 0; m < 4; ++m) {
          const int row = wr * 64 + m * 16 + lr;
          const int slot = ks * 4 + g;
          af[m] = *reinterpret_cast<const bf16x8*>(Ab + row * 128 +
                                                   ((slot ^ (row & 7)) << 4));
        }
#pragma unroll
        for (int n = 0; n < 4; ++n) {
          const int col = wc * 64 + n * 16 + lr;
          const int slot = ks * 4 + g;
          bfr[n] = *reinterpret_cast<const bf16x8*>(Bb + col * 128 +
                                                    ((slot ^ (col & 7)) << 4));
        }
#pragma unroll
        for (int m = 0; m < 4; ++m)
#pragma unroll
          for (int n = 0; n < 4; ++n)
            acc[m][n] =
                __builtin_amdgcn_mfma_f32_16x16x32_bf16(af[m], bfr[n], acc[m][n], 0, 0, 0);
      }
    }

    if (nt == 0) {
#pragma unroll
      for (int c = 0; c < 8; ++c) {
        float ss = sqpart[c];
        ss += __shfl_xor(ss, 1);
        ss += __shfl_xor(ss, 2);
        ss += __shfl_xor(ss, 4);
        ss += __shfl_xor(ss, 8);
        if (lr == 0) sqrow[c * 16 + (w * 4 + g)] = ss;
      }
    }
    if constexpr (!WS) {
#pragma unroll
      for (int c = 0; c < 8; ++c) {
        float ss = cpart[c];
        ss += __shfl_xor(ss, 1);
        ss += __shfl_xor(ss, 2);
        ss += __shfl_xor(ss, 4);
        ss += __shfl_xor(ss, 8);
        if (lr == 0) colsq[c * 16 + (w * 4 + g)] = ss;
      }
      __syncthreads();
    }

#pragma unroll
    for (int n = 0; n < 4; ++n) {
      float cs;
      if constexpr (WS)
        cs = csq[col0 + wc * 64 + n * 16 + lr];
      else
        cs = colsq[wc * 64 + n * 16 + lr];
#pragma unroll
      for (int m = 0; m < 4; ++m)
#pragma unroll
        for (int r = 0; r < 4; ++r)
          runmin[m][r] = fminf(runmin[m][r], cs - 2.0f * acc[m][n][r]);
    }
  }

#pragma unroll
  for (int m = 0; m < 4; ++m)
#pragma unroll
    for (int r = 0; r < 4; ++r) {
      float v = runmin[m][r];
      v = fminf(v, __shfl_xor(v, 1));
      v = fminf(v, __shfl_xor(v, 2));
      v = fminf(v, __shfl_xor(v, 4));
      v = fminf(v, __shfl_xor(v, 8));
      runmin[m][r] = v;
    }
  if (lr == 0) {
#pragma unroll
    for (int m = 0; m < 4; ++m)
#pragma unroll
      for (int r = 0; r < 4; ++r)
        rowmin2[wc][wr * 64 + m * 16 + g * 4 + r] = runmin[m][r];
  }
  __syncthreads();
  if (t < TM) {
    const float v = fminf(rowmin2[0][t], rowmin2[1][t]);
    out[row0 + t] = sqrtf(fmaxf(sqrow[t] + v, 0.f));
  }
}

extern "C" void kernel_launch(void* const* d_in, const int* in_sizes, int n_in,
                              void* d_out, int out_size, void* d_ws, size_t ws_size,
                              hipStream_t stream) {
  const float* embeds = (const float*)d_in[0];
  const float* cent = (const float*)d_in[1];
  float* out = (float*)d_out;

  // ws layout for the fp8 fast path (~112 MiB)
  const size_t off_c8 = 0;
  const size_t off_csq = off_c8 + (size_t)M_CENT * D_K;             // 2 MiB
  const size_t off_e8 = off_csq + (size_t)M_CENT * 4;               // +8 KiB
  const size_t off_esq = off_e8 + (size_t)N_ROWS * D_K;             // +98 MiB
  const size_t off_pmin = off_esq + (size_t)N_ROWS * 4;             // +392 KiB
  const size_t need_full = off_pmin + (size_t)N_ROWS * NCT4 * 4;    // +6.1 MiB
  const size_t need_small = (size_t)M_CENT * D_K * 2 + (size_t)M_CENT * 4;

  if (ws_size >= need_full) {
    unsigned char* c8 = (unsigned char*)d_ws + off_c8;
    float* csq = (float*)((char*)d_ws + off_csq);
    unsigned char* e8 = (unsigned char*)d_ws + off_e8;
    float* esq = (float*)((char*)d_ws + off_esq);
    float* pmin = (float*)((char*)d_ws + off_pmin);
    rowsq_fp8pack<<<M_CENT, 256, 0, stream>>>(cent, c8, csq);
    rowsq_fp8pack<<<N_ROWS, 256, 0, stream>>>(embeds, e8, esq);
    gemm_min_mx<<<NBLK4, 256, 0, stream>>>(e8, c8, csq, pmin);
    final_min<<<N_ROWS / 256, 256, 0, stream>>>(esq, pmin, out);
  } else if (ws_size >= need_small) {
    __bf16* cbf = (__bf16*)d_ws;
    float* csq = (float*)((char*)d_ws + (size_t)M_CENT * D_K * 2);
    rowsq_bf16<<<M_CENT, 256, 0, stream>>>(cent, cbf, csq);
    fused_min<true><<<N_ROWS / TM, 256, 0, stream>>>(embeds, cent, cbf, csq, out);
  } else {
    fused_min<false><<<N_ROWS / TM, 256, 0, stream>>>(embeds, cent, nullptr, nullptr, out);
  }
}